// Round 2
// baseline (724.701 us; speedup 1.0000x reference)
//
#include <hip/hip_runtime.h>
#include <math.h>

static constexpr int  Bb = 8;
static constexpr int  L  = 2048;
static constexpr int  H  = 256;
static constexpr long BL = (long)Bb * L;   // 16384
static constexpr int  NCH = 16;            // i-chunks for column stats
static constexpr int  ICH = L / NCH;       // 128

// ---------------------------------------------------------------------------
// NT GEMM: C[m,n] = sum_k A[m,k] * B[n,k]; A: MxK row-major, B: NxK row-major.
// 64x64 tile, BK=16, 256 threads, 4x4 per thread, fp32.
// ---------------------------------------------------------------------------
__global__ __launch_bounds__(256)
void gemm_nt(const float* __restrict__ A, const float* __restrict__ B,
             float* __restrict__ C, int M, int N, int K,
             long sA, long sB, long sC)
{
    constexpr int BM = 64, BN = 64, BK = 16;
    __shared__ float As[BK][BM];
    __shared__ float Bs[BK][BN];
    const int tid = threadIdx.x;
    const long b = blockIdx.z;
    A += b * sA; B += b * sB; C += b * sC;
    const int m0 = blockIdx.x * BM, n0 = blockIdx.y * BN;
    const int lr = tid >> 2, lk = (tid & 3) << 2;   // tile loads: row, k-offset
    const int tm = (tid >> 4) << 2, tn = (tid & 15) << 2;
    float acc[4][4] = {};
    for (int k0 = 0; k0 < K; k0 += BK) {
        float4 a4 = *(const float4*)(A + (long)(m0 + lr) * K + (k0 + lk));
        float4 b4 = *(const float4*)(B + (long)(n0 + lr) * K + (k0 + lk));
        __syncthreads();
        As[lk + 0][lr] = a4.x; As[lk + 1][lr] = a4.y;
        As[lk + 2][lr] = a4.z; As[lk + 3][lr] = a4.w;
        Bs[lk + 0][lr] = b4.x; Bs[lk + 1][lr] = b4.y;
        Bs[lk + 2][lr] = b4.z; Bs[lk + 3][lr] = b4.w;
        __syncthreads();
#pragma unroll
        for (int kk = 0; kk < BK; ++kk) {
            float4 av = *(const float4*)&As[kk][tm];
            float4 bv = *(const float4*)&Bs[kk][tn];
            float ar[4] = {av.x, av.y, av.z, av.w};
            float br[4] = {bv.x, bv.y, bv.z, bv.w};
#pragma unroll
            for (int i = 0; i < 4; ++i)
#pragma unroll
                for (int j = 0; j < 4; ++j)
                    acc[i][j] = fmaf(ar[i], br[j], acc[i][j]);
        }
    }
#pragma unroll
    for (int i = 0; i < 4; ++i) {
        float4 o = {acc[i][0], acc[i][1], acc[i][2], acc[i][3]};
        *(float4*)(C + (long)(m0 + tm + i) * N + (n0 + tn)) = o;
    }
}

// ---------------------------------------------------------------------------
// Column softmax stats over axis=1 (i) for each (b, j), chunked over i.
// ---------------------------------------------------------------------------
__global__ __launch_bounds__(256)
void col_stats_partial(const float* __restrict__ S, float* __restrict__ pm,
                       float* __restrict__ pz)
{
    const int b = blockIdx.z, ch = blockIdx.y;
    const int j = blockIdx.x * 256 + threadIdx.x;
    const float* Sb = S + (long)b * L * L;
    float m = -1e30f, z = 0.f;
    for (int i = ch * ICH; i < ch * ICH + ICH; ++i) {
        float s  = Sb[(long)i * L + j];
        float mn = fmaxf(m, s);
        z = z * __expf(m - mn) + __expf(s - mn);
        m = mn;
    }
    long o = ((long)b * NCH + ch) * L + j;
    pm[o] = m; pz[o] = z;
}

__global__ __launch_bounds__(256)
void col_stats_reduce(const float* __restrict__ pm, const float* __restrict__ pz,
                      float* __restrict__ ms, float* __restrict__ zi)
{
    const long idx = (long)blockIdx.x * 256 + threadIdx.x;   // b*L + j
    const long b = idx / L, j = idx - b * L;
    const float* pmb = pm + b * (long)NCH * L + j;
    const float* pzb = pz + b * (long)NCH * L + j;
    float m = -1e30f;
#pragma unroll
    for (int c = 0; c < NCH; ++c) m = fmaxf(m, pmb[(long)c * L]);
    float z = 0.f;
#pragma unroll
    for (int c = 0; c < NCH; ++c) z += pzb[(long)c * L] * __expf(pmb[(long)c * L] - m);
    ms[idx] = m;
    zi[idx] = 1.f / z;
}

// ---------------------------------------------------------------------------
// c[b,i,h] = sum_j exp(S[b,i,j]-m[b,j])*zi[b,j] * g[b,j,h]
// NN GEMM, M=L, N=H(=256, full width), K=L. 64x256 tile, BK=16.
// ---------------------------------------------------------------------------
__global__ __launch_bounds__(256)
void gemm_av(const float* __restrict__ S, const float* __restrict__ ms,
             const float* __restrict__ zi, const float* __restrict__ g,
             float* __restrict__ Cb)
{
    constexpr int BM = 64, BK = 16;
    __shared__ float As[BK][BM];
    __shared__ float Bs[BK][H];
    const int tid = threadIdx.x;
    const int b = blockIdx.z;
    const float* Sb  = S  + (long)b * L * L;
    const float* gb  = g  + (long)b * L * H;
    const float* msb = ms + (long)b * L;
    const float* zib = zi + (long)b * L;
    float* Cbb = Cb + (long)b * L * H;
    const int m0 = blockIdx.x * BM;
    const int lr = tid >> 2, lk = (tid & 3) << 2;    // A load (i-row, j-off)
    const int jr = tid >> 4, nc = (tid & 15) << 2;   // B load (j-row, h-off)
    const int tm = (tid >> 4) << 2, tn = (tid & 15) << 2;
    float acc[4][16] = {};
    for (int k0 = 0; k0 < L; k0 += BK) {
        float4 s4 = *(const float4*)(Sb + (long)(m0 + lr) * L + (k0 + lk));
        float4 m4 = *(const float4*)(msb + k0 + lk);
        float4 z4 = *(const float4*)(zib + k0 + lk);
        float4 bv0 = *(const float4*)(gb + (long)(k0 + jr) * H + nc +   0);
        float4 bv1 = *(const float4*)(gb + (long)(k0 + jr) * H + nc +  64);
        float4 bv2 = *(const float4*)(gb + (long)(k0 + jr) * H + nc + 128);
        float4 bv3 = *(const float4*)(gb + (long)(k0 + jr) * H + nc + 192);
        float4 a4;
        a4.x = __expf(s4.x - m4.x) * z4.x;
        a4.y = __expf(s4.y - m4.y) * z4.y;
        a4.z = __expf(s4.z - m4.z) * z4.z;
        a4.w = __expf(s4.w - m4.w) * z4.w;
        __syncthreads();
        As[lk + 0][lr] = a4.x; As[lk + 1][lr] = a4.y;
        As[lk + 2][lr] = a4.z; As[lk + 3][lr] = a4.w;
        *(float4*)&Bs[jr][nc +   0] = bv0;
        *(float4*)&Bs[jr][nc +  64] = bv1;
        *(float4*)&Bs[jr][nc + 128] = bv2;
        *(float4*)&Bs[jr][nc + 192] = bv3;
        __syncthreads();
#pragma unroll
        for (int kk = 0; kk < BK; ++kk) {
            float4 av = *(const float4*)&As[kk][tm];
            float ar[4] = {av.x, av.y, av.z, av.w};
#pragma unroll
            for (int c = 0; c < 4; ++c) {
                float4 bv2r = *(const float4*)&Bs[kk][tn + 64 * c];
                float br[4] = {bv2r.x, bv2r.y, bv2r.z, bv2r.w};
#pragma unroll
                for (int i = 0; i < 4; ++i)
#pragma unroll
                    for (int q = 0; q < 4; ++q)
                        acc[i][c * 4 + q] = fmaf(ar[i], br[q], acc[i][c * 4 + q]);
            }
        }
    }
#pragma unroll
    for (int i = 0; i < 4; ++i)
#pragma unroll
        for (int c = 0; c < 4; ++c) {
            float4 o = {acc[i][c*4+0], acc[i][c*4+1], acc[i][c*4+2], acc[i][c*4+3]};
            *(float4*)(Cbb + (long)(m0 + tm + i) * H + tn + 64 * c) = o;
        }
}

// ---------------------------------------------------------------------------
// out[bl,o] = relu(b[o] + sum_h g*W1 + c*W2 + (g.c)*W3); NT GEMM with
// synthesized A (K=768 in 3 segments of 256).
// ---------------------------------------------------------------------------
__global__ __launch_bounds__(256)
void gemm_out(const float* __restrict__ g, const float* __restrict__ Cb,
              const float* __restrict__ W, const float* __restrict__ bias,
              float* __restrict__ out)
{
    constexpr int BM = 64, BN = 64, BK = 16, K = 3 * H;
    __shared__ float As[BK][BM];
    __shared__ float Bs[BK][BN];
    const int tid = threadIdx.x;
    const int m0 = blockIdx.x * BM, n0 = blockIdx.y * BN;
    const int lr = tid >> 2, lk = (tid & 3) << 2;
    const int tm = (tid >> 4) << 2, tn = (tid & 15) << 2;
    float acc[4][4] = {};
    for (int k0 = 0; k0 < K; k0 += BK) {
        const int seg = k0 >> 8;
        const int kc  = (k0 & 255) + lk;
        const long rowoff = (long)(m0 + lr) * H + kc;
        float4 a4;
        if (seg == 0) {
            a4 = *(const float4*)(g + rowoff);
        } else if (seg == 1) {
            a4 = *(const float4*)(Cb + rowoff);
        } else {
            float4 x = *(const float4*)(g + rowoff);
            float4 y = *(const float4*)(Cb + rowoff);
            a4.x = x.x * y.x; a4.y = x.y * y.y; a4.z = x.z * y.z; a4.w = x.w * y.w;
        }
        float4 b4 = *(const float4*)(W + (long)(n0 + lr) * K + (k0 + lk));
        __syncthreads();
        As[lk + 0][lr] = a4.x; As[lk + 1][lr] = a4.y;
        As[lk + 2][lr] = a4.z; As[lk + 3][lr] = a4.w;
        Bs[lk + 0][lr] = b4.x; Bs[lk + 1][lr] = b4.y;
        Bs[lk + 2][lr] = b4.z; Bs[lk + 3][lr] = b4.w;
        __syncthreads();
#pragma unroll
        for (int kk = 0; kk < BK; ++kk) {
            float4 av = *(const float4*)&As[kk][tm];
            float4 bv = *(const float4*)&Bs[kk][tn];
            float ar[4] = {av.x, av.y, av.z, av.w};
            float br[4] = {bv.x, bv.y, bv.z, bv.w};
#pragma unroll
            for (int i = 0; i < 4; ++i)
#pragma unroll
                for (int j = 0; j < 4; ++j)
                    acc[i][j] = fmaf(ar[i], br[j], acc[i][j]);
        }
    }
    float4 bb = *(const float4*)(bias + n0 + tn);
    float bs[4] = {bb.x, bb.y, bb.z, bb.w};
#pragma unroll
    for (int i = 0; i < 4; ++i) {
        float4 o = {fmaxf(acc[i][0] + bs[0], 0.f), fmaxf(acc[i][1] + bs[1], 0.f),
                    fmaxf(acc[i][2] + bs[2], 0.f), fmaxf(acc[i][3] + bs[3], 0.f)};
        *(float4*)(out + (long)(m0 + tm + i) * H + (n0 + tn)) = o;
    }
}

// ---------------------------------------------------------------------------
extern "C" void kernel_launch(void* const* d_in, const int* in_sizes, int n_in,
                              void* d_out, int out_size, void* d_ws, size_t ws_size,
                              hipStream_t stream)
{
    const float* g     = (const float*)d_in[0];
    const float* WP    = (const float*)d_in[1];
    const float* W_out = (const float*)d_in[2];
    const float* b_out = (const float*)d_in[3];
    float* out = (float*)d_out;

    float* ws  = (float*)d_ws;
    float* Wh  = ws;                          // BL*H          = 4,194,304
    float* S   = Wh  + BL * H;                // Bb*L*L        = 33,554,432
    float* Cb  = S   + (long)Bb * L * L;      // BL*H          = 4,194,304
    float* pm  = Cb  + BL * H;                // Bb*NCH*L      = 262,144
    float* pz  = pm  + (long)Bb * NCH * L;    // 262,144
    float* msv = pz  + (long)Bb * NCH * L;    // BL = 16,384
    float* ziv = msv + BL;                    // 16,384

    // K1: Wh = g @ WP^T   [BL,H] x [H,H]
    gemm_nt<<<dim3(BL / 64, H / 64, 1), 256, 0, stream>>>(
        g, WP, Wh, (int)BL, H, H, 0, 0, 0);
    // K2: S[b] = Wh[b] @ g[b]^T   [L,H] x [L,H]^T -> [L,L]
    gemm_nt<<<dim3(L / 64, L / 64, Bb), 256, 0, stream>>>(
        Wh, g, S, L, L, H, (long)L * H, (long)L * H, (long)L * L);
    // K3: column softmax stats (over i, per (b,j))
    col_stats_partial<<<dim3(L / 256, NCH, Bb), 256, 0, stream>>>(S, pm, pz);
    col_stats_reduce<<<dim3((int)(BL / 256)), 256, 0, stream>>>(pm, pz, msv, ziv);
    // K4: c = softmax(S) @ g
    gemm_av<<<dim3(L / 64, 1, Bb), 256, 0, stream>>>(S, msv, ziv, g, Cb);
    // K5: out = relu([g, c, g*c] @ W_out^T + b)
    gemm_out<<<dim3((int)(BL / 64), H / 64, 1), 256, 0, stream>>>(
        g, Cb, W_out, b_out, out);
}

// Round 3
// 311.307 us; speedup vs baseline: 2.3279x; 2.3279x over previous
//
#include <hip/hip_runtime.h>
#include <math.h>

static constexpr int  Bb = 8;
static constexpr int  L  = 2048;
static constexpr int  H  = 256;
static constexpr long BL = (long)Bb * L;     // 16384
static constexpr long LH = (long)L * H;      // 524288
static constexpr long LL = (long)L * L;      // 4194304
static constexpr int  NCH = 16;
static constexpr int  ICH = L / NCH;

typedef __attribute__((ext_vector_type(8))) unsigned short u16x8;
typedef __attribute__((ext_vector_type(4))) unsigned short u16x4;
typedef __attribute__((ext_vector_type(8))) short          bf16x8;
typedef __attribute__((ext_vector_type(4))) float          f32x4;

__device__ __forceinline__ unsigned short f2bf(float x) {
    union { float f; unsigned u; } v; v.f = x;
    unsigned r = v.u + 0x7fffu + ((v.u >> 16) & 1u);   // RNE
    return (unsigned short)(r >> 16);
}
__device__ __forceinline__ float bf2f(unsigned short h) {
    union { unsigned u; float f; } v; v.u = ((unsigned)h) << 16;
    return v.f;
}

// ---------------------------------------------------------------------------
// split fp32 -> bf16 hi + bf16 lo  (x ~= hi + lo)
// ---------------------------------------------------------------------------
__global__ __launch_bounds__(256)
void split_bf(const float* __restrict__ x, unsigned short* __restrict__ hi,
              unsigned short* __restrict__ lo)
{
    const long i = ((long)blockIdx.x * 256 + threadIdx.x) * 4;
    float4 v = *(const float4*)(x + i);
    u16x4 h, l;
    float vv[4] = {v.x, v.y, v.z, v.w};
#pragma unroll
    for (int e = 0; e < 4; ++e) {
        unsigned short hh = f2bf(vv[e]);
        h[e] = hh;
        l[e] = f2bf(vv[e] - bf2f(hh));
    }
    *(u16x4*)(hi + i) = h;
    *(u16x4*)(lo + i) = l;
}

// ---------------------------------------------------------------------------
// 32x32-tiled bf16 transpose per batch: gT[b][h][j] = g[b][j][h]
// ---------------------------------------------------------------------------
__global__ __launch_bounds__(256)
void transpose_bf16(const unsigned short* __restrict__ in, unsigned short* __restrict__ out)
{
    __shared__ unsigned short T[32][33];
    const int b = blockIdx.z, j0 = blockIdx.x * 32, h0 = blockIdx.y * 32;
    const int t = threadIdx.x, r = t >> 3, c4 = (t & 7) << 2;
    const unsigned short* inb = in + (long)b * LH;
    unsigned short* outb = out + (long)b * LH;
    u16x4 v = *(const u16x4*)(inb + (long)(j0 + r) * H + h0 + c4);
#pragma unroll
    for (int e = 0; e < 4; ++e) T[r][c4 + e] = v[e];
    __syncthreads();
    u16x4 w;
#pragma unroll
    for (int e = 0; e < 4; ++e) w[e] = T[c4 + e][r];
    *(u16x4*)(outb + (long)(h0 + r) * L + j0 + c4) = w;
}

// ---------------------------------------------------------------------------
// Column softmax stats over axis=1 (i) for each (b, j), chunked over i.
// ---------------------------------------------------------------------------
__global__ __launch_bounds__(256)
void col_stats_partial(const float* __restrict__ S, float* __restrict__ pm,
                       float* __restrict__ pz)
{
    const int b = blockIdx.z, ch = blockIdx.y;
    const int j = blockIdx.x * 256 + threadIdx.x;
    const float* Sb = S + (long)b * LL;
    float m = -1e30f, z = 0.f;
    for (int i = ch * ICH; i < ch * ICH + ICH; ++i) {
        float s  = Sb[(long)i * L + j];
        float mn = fmaxf(m, s);
        z = z * __expf(m - mn) + __expf(s - mn);
        m = mn;
    }
    long o = ((long)b * NCH + ch) * L + j;
    pm[o] = m; pz[o] = z;
}

__global__ __launch_bounds__(256)
void col_stats_reduce(const float* __restrict__ pm, const float* __restrict__ pz,
                      float* __restrict__ ms, float* __restrict__ zi)
{
    const long idx = (long)blockIdx.x * 256 + threadIdx.x;   // b*L + j
    const long b = idx / L, j = idx - b * L;
    const float* pmb = pm + b * (long)NCH * L + j;
    const float* pzb = pz + b * (long)NCH * L + j;
    float m = -1e30f;
#pragma unroll
    for (int c = 0; c < NCH; ++c) m = fmaxf(m, pmb[(long)c * L]);
    float z = 0.f;
#pragma unroll
    for (int c = 0; c < NCH; ++c) z += pzb[(long)c * L] * __expf(pmb[(long)c * L] - m);
    ms[idx] = m;
    zi[idx] = 1.f / z;
}

// ---------------------------------------------------------------------------
// Unified NT MFMA GEMM, 128x128 tile, K = 3 segments of 256, BK=32.
// C[m,n] = sum_seg sum_k Aseg[m,k] * Bseg[n,k]
// MODE 0: fp32 C, optional batch strides (K1: Wh, K2: S)
// MODE 1: seg2 A synthesized as bf16(A0*A1), epilogue bias+relu (K5: out)
// ---------------------------------------------------------------------------
template<int MODE>
__global__ __launch_bounds__(256)
void mfma_nt(const unsigned short* A0, const unsigned short* A1, const unsigned short* A2,
             const unsigned short* B0, const unsigned short* B1, const unsigned short* B2,
             float* __restrict__ C, const float* __restrict__ bias,
             int N, int lda, int ldb,
             long strideA, long strideB, long strideC)
{
    __shared__ __align__(16) unsigned short As[128][32];
    __shared__ __align__(16) unsigned short Bs[128][32];
    const int tid  = threadIdx.x;
    const int wid  = tid >> 6, lane = tid & 63;
    const int wm   = wid >> 1, wn = wid & 1;
    const long b   = blockIdx.z;
    const int m0   = blockIdx.x * 128, n0 = blockIdx.y * 128;
    const int lrow = tid >> 2, lkc = (tid & 3) << 3;
    const int frow = lane & 15, fk = (lane >> 4) << 3;
    f32x4 acc[4][4];
#pragma unroll
    for (int i = 0; i < 4; ++i)
#pragma unroll
        for (int j = 0; j < 4; ++j) acc[i][j] = (f32x4){0.f, 0.f, 0.f, 0.f};

    const long abase = b * strideA, bbase = b * strideB;

    for (int seg = 0; seg < 3; ++seg) {
        const unsigned short* Ap = (seg == 0) ? A0 : ((seg == 1) ? A1 : A2);
        const unsigned short* Bp = (seg == 0) ? B0 : ((seg == 1) ? B1 : B2);
        for (int k0 = 0; k0 < 256; k0 += 32) {
            __syncthreads();
#pragma unroll
            for (int r = 0; r < 2; ++r) {
                const int row = lrow + (r << 6);
                u16x8 av;
                if (MODE == 1 && seg == 2) {
                    const long off = (long)(m0 + row) * lda + k0 + lkc;
                    u16x8 gv = *(const u16x8*)(A0 + off);
                    u16x8 cv = *(const u16x8*)(A1 + off);
#pragma unroll
                    for (int e = 0; e < 8; ++e)
                        av[e] = f2bf(bf2f(gv[e]) * bf2f(cv[e]));
                } else {
                    av = *(const u16x8*)(Ap + abase + (long)(m0 + row) * lda + k0 + lkc);
                }
                *(u16x8*)&As[row][lkc] = av;
                u16x8 bv = *(const u16x8*)(Bp + bbase + (long)(n0 + row) * ldb + k0 + lkc);
                *(u16x8*)&Bs[row][lkc] = bv;
            }
            __syncthreads();
            bf16x8 af[4], bfv[4];
#pragma unroll
            for (int i = 0; i < 4; ++i) af[i]  = *(const bf16x8*)&As[wm * 64 + i * 16 + frow][fk];
#pragma unroll
            for (int j = 0; j < 4; ++j) bfv[j] = *(const bf16x8*)&Bs[wn * 64 + j * 16 + frow][fk];
#pragma unroll
            for (int i = 0; i < 4; ++i)
#pragma unroll
                for (int j = 0; j < 4; ++j)
                    acc[i][j] = __builtin_amdgcn_mfma_f32_16x16x32_bf16(af[i], bfv[j], acc[i][j], 0, 0, 0);
        }
    }

    float* Cb = C + b * strideC;
#pragma unroll
    for (int i = 0; i < 4; ++i)
#pragma unroll
        for (int j = 0; j < 4; ++j) {
            const int rbase = m0 + wm * 64 + i * 16 + ((lane >> 4) << 2);
            const int col   = n0 + wn * 64 + j * 16 + frow;
            const float bv  = (MODE == 1) ? bias[col] : 0.f;
#pragma unroll
            for (int e = 0; e < 4; ++e) {
                float v = acc[i][j][e];
                if (MODE == 1) v = fmaxf(v + bv, 0.f);
                Cb[(long)(rbase + e) * N + col] = v;
            }
        }
}

// ---------------------------------------------------------------------------
// c[b,i,h] = sum_j exp(S[b,i,j]-m[b,j])*zi[b,j] * g[b,j,h]  -> bf16 chh
// Tile 128(i) x 256(h, full) x BK=32(j); 512 threads, 8 waves (2x4).
// A staged from S fp32 with on-the-fly exp -> bf16; B staged from gT bf16.
// ---------------------------------------------------------------------------
__global__ __launch_bounds__(512)
void attn_av(const float* __restrict__ S, const float* __restrict__ ms,
             const float* __restrict__ zi, const unsigned short* __restrict__ gT,
             unsigned short* __restrict__ chh)
{
    __shared__ __align__(16) unsigned short As[128][32];
    __shared__ __align__(16) unsigned short Bs[256][32];
    const int t = threadIdx.x, b = blockIdx.z;
    const int i0 = blockIdx.x * 128;
    const float* Sb = S + (long)b * LL;
    const unsigned short* gTb = gT + (long)b * LH;
    unsigned short* cb = chh + (long)b * LH;
    const float* msb = ms + (long)b * L;
    const float* zib = zi + (long)b * L;
    const int wid = t >> 6, lane = t & 63;
    const int wm = wid >> 2, wn = wid & 3;
    const int frow = lane & 15, fk = (lane >> 4) << 3;
    const int ar = t >> 3, ac = (t & 7) << 2;   // A staging: 64 rows x 8 chunks(4)
    const int br = t >> 2, bc = (t & 3) << 3;   // B staging: 128 rows x 4 chunks(8)
    f32x4 acc[4][4];
#pragma unroll
    for (int i = 0; i < 4; ++i)
#pragma unroll
        for (int j = 0; j < 4; ++j) acc[i][j] = (f32x4){0.f, 0.f, 0.f, 0.f};

    for (int j0 = 0; j0 < L; j0 += 32) {
        __syncthreads();
        float4 m4 = *(const float4*)(msb + j0 + ac);
        float4 z4 = *(const float4*)(zib + j0 + ac);
#pragma unroll
        for (int r = 0; r < 2; ++r) {
            const int row = ar + (r << 6);
            float4 s4 = *(const float4*)(Sb + (long)(i0 + row) * L + j0 + ac);
            u16x4 a;
            a[0] = f2bf(__expf(s4.x - m4.x) * z4.x);
            a[1] = f2bf(__expf(s4.y - m4.y) * z4.y);
            a[2] = f2bf(__expf(s4.z - m4.z) * z4.z);
            a[3] = f2bf(__expf(s4.w - m4.w) * z4.w);
            *(u16x4*)&As[row][ac] = a;
        }
#pragma unroll
        for (int r = 0; r < 2; ++r) {
            const int row = br + (r << 7);
            *(u16x8*)&Bs[row][bc] = *(const u16x8*)(gTb + (long)row * L + j0 + bc);
        }
        __syncthreads();
        bf16x8 af[4], bfv[4];
#pragma unroll
        for (int i = 0; i < 4; ++i) af[i]  = *(const bf16x8*)&As[wm * 64 + i * 16 + frow][fk];
#pragma unroll
        for (int j = 0; j < 4; ++j) bfv[j] = *(const bf16x8*)&Bs[wn * 64 + j * 16 + frow][fk];
#pragma unroll
        for (int i = 0; i < 4; ++i)
#pragma unroll
            for (int j = 0; j < 4; ++j)
                acc[i][j] = __builtin_amdgcn_mfma_f32_16x16x32_bf16(af[i], bfv[j], acc[i][j], 0, 0, 0);
    }
#pragma unroll
    for (int i = 0; i < 4; ++i)
#pragma unroll
        for (int j = 0; j < 4; ++j) {
            const int rbase = i0 + wm * 64 + i * 16 + ((lane >> 4) << 2);
            const int col   = wn * 64 + j * 16 + frow;
#pragma unroll
            for (int e = 0; e < 4; ++e)
                cb[(long)(rbase + e) * H + col] = f2bf(acc[i][j][e]);
        }
}

// ---------------------------------------------------------------------------
extern "C" void kernel_launch(void* const* d_in, const int* in_sizes, int n_in,
                              void* d_out, int out_size, void* d_ws, size_t ws_size,
                              hipStream_t stream)
{
    const float* g     = (const float*)d_in[0];
    const float* WP    = (const float*)d_in[1];
    const float* W_out = (const float*)d_in[2];
    const float* b_out = (const float*)d_in[3];
    float* out = (float*)d_out;

    // ---- workspace layout (bytes), lifetime-aliased, total ~163 MB ----
    char* w = (char*)d_ws;
    float*          S    = (float*)w;                           // [0, 128M)
    float*          Whf  = (float*)w;                           // alias: dead before S written
    unsigned short* ghh  = (unsigned short*)(w + 134217728);    // 8 MB
    unsigned short* ghl  = (unsigned short*)(w + 142606336);    // 8 MB (dead after K2)
    unsigned short* chh  = ghl;                                 // alias: written by K4
    unsigned short* Whhh = (unsigned short*)(w + 150994944);    // 8 MB (dead after K2)
    unsigned short* gT   = Whhh;                                // alias: written after K2
    unsigned short* Whl  = (unsigned short*)(w + 159383552);    // 8 MB
    unsigned short* WPhh = (unsigned short*)(w + 167772160);    // 128 KB
    unsigned short* WPhl = (unsigned short*)(w + 167903232);    // 128 KB
    unsigned short* Wob  = (unsigned short*)(w + 168034304);    // 384 KB
    unsigned short* Wol  = (unsigned short*)(w + 168427520);    // 384 KB (unused lo)
    float*          pm   = (float*)(w + 168820736);             // 1 MB
    float*          pz   = (float*)(w + 169869312);             // 1 MB
    float*          msv  = (float*)(w + 170917888);             // 64 KB
    float*          ziv  = (float*)(w + 170983424);             // 64 KB

    // 1) splits / converts
    split_bf<<<dim3((int)(BL * H / 1024)), 256, 0, stream>>>(g, ghh, ghl);
    split_bf<<<dim3(H * H / 1024), 256, 0, stream>>>(WP, WPhh, WPhl);
    split_bf<<<dim3(H * 3 * H / 1024), 256, 0, stream>>>(W_out, Wob, Wol);

    // 2) K1: Wh = g @ WP^T  (split 3-term, fp32 out into Whf)
    mfma_nt<0><<<dim3((int)(BL / 128), H / 128, 1), 256, 0, stream>>>(
        ghh, ghl, ghh, WPhh, WPhh, WPhl, Whf, nullptr, H, H, H, 0, 0, 0);

    // 3) split Wh
    split_bf<<<dim3((int)(BL * H / 1024)), 256, 0, stream>>>(Whf, Whhh, Whl);

    // 4) K2: S[b] = Wh[b] @ g[b]^T  (split 3-term, fp32 S)
    mfma_nt<0><<<dim3(L / 128, L / 128, Bb), 256, 0, stream>>>(
        Whhh, Whl, Whhh, ghh, ghh, ghl, S, nullptr, L, H, H, LH, LH, LL);

    // 5) column softmax stats
    col_stats_partial<<<dim3(L / 256, NCH, Bb), 256, 0, stream>>>(S, pm, pz);
    col_stats_reduce<<<dim3((int)(BL / 256)), 256, 0, stream>>>(pm, pz, msv, ziv);

    // 6) transpose ghh -> gT (after K2: gT aliases Whhh)
    transpose_bf16<<<dim3(L / 32, H / 32, Bb), 256, 0, stream>>>(ghh, gT);

    // 7) K4: c = softmax_col(S) @ g  -> chh (bf16)
    attn_av<<<dim3(L / 128, 1, Bb), 512, 0, stream>>>(S, msv, ziv, gT, chh);

    // 8) K5: out = relu([g, c, g*c] @ W_out^T + b)
    mfma_nt<1><<<dim3((int)(BL / 128), H / 128, 1), 256, 0, stream>>>(
        ghh, chh, nullptr, Wob, Wob + 256, Wob + 512, out, b_out, H, H, 3 * H, 0, 0, 0);
}